// Round 13
// baseline (393.437 us; speedup 1.0000x reference)
//
#include <hip/hip_runtime.h>
#include <hip/hip_bf16.h>
#include <hip/hip_fp16.h>

// TargetNet: per-sample MLP 2048->1024->512->256->128->1 over 64 samples x 256 spatial.
// R13 = R11 (304.9 us, best) + non-temporal W loads. R12's spin-barrier fusion
// regressed (+40 us) and is reverted.
// Theory: W streams (537+134+34+8 MB, read-once) allocate through L3 and evict the
// small re-read tensors (xT 67 MB, h1 34 MB...), forcing MT re-reads to HBM. nt
// (no-allocate) on W keeps activations L3-resident -> re-reads become L3 hits.

typedef __attribute__((ext_vector_type(4)))  float    f32x4;
typedef __attribute__((ext_vector_type(16))) float    f32x16;
typedef __attribute__((ext_vector_type(8)))  short    short8;
typedef __attribute__((ext_vector_type(4)))  short    short4v;
typedef __attribute__((ext_vector_type(8)))  _Float16 half8;

__device__ __forceinline__ unsigned short f2h_bits(float f) {
  return __builtin_bit_cast(unsigned short, (_Float16)f);
}
__device__ __forceinline__ float h2f(short h) {
  return (float)__builtin_bit_cast(_Float16, (unsigned short)h);
}

// ---- transpose + convert: x [64][2048][256] f32 -> xT [64][256][2048] f16 ----
__global__ __launch_bounds__(256) void transpose_cvt(const float* __restrict__ X,
                                                     short* __restrict__ XT) {
  __shared__ float tile[32][33];
  const int b  = blockIdx.z;
  const int c0 = blockIdx.x * 32, s0 = blockIdx.y * 32;
  const int tl = threadIdx.x & 31, tw = threadIdx.x >> 5;  // tw: 0..7
  const float* xp = X + ((size_t)b * 2048 + c0) * 256 + s0;
#pragma unroll
  for (int i = 0; i < 4; ++i) {
    const int c = tw * 4 + i;
    tile[c][tl] = __builtin_nontemporal_load(&xp[(size_t)c * 256 + tl]);  // x read once: nt
  }
  __syncthreads();
  short* op = XT + ((size_t)(b * 256 + s0)) * 2048 + c0;
#pragma unroll
  for (int i = 0; i < 4; ++i) {
    const int s = tw * 4 + i;
    op[(size_t)s * 2048 + tl] = (short)f2h_bits(tile[tl][s]);  // xT write: cacheable (re-read 4x)
  }
}

// ---- per-sample GEMM layer with fused bias+sigmoid (optional fused fc5 tail) ----
// C[s, m] = sigmoid( sum_k W[m,k] * X[s,k] + bias[m] ), per sample b.
// A frag: lane l holds row (l&31), k = (l>>5)*8 + j   (f16 cvt from fp32 W, nt-streamed once)
// B frag: lane l holds col (l&31), k = (l>>5)*8 + j   (16B ds_read from frag-ready LDS)
// C frag: col = lane&31, row = (reg&3) + 8*(reg>>2) + 4*(lane>>5)
template <int BK> struct WFrag { f32x4 v[BK / 8]; };

template <int M, int K, int WAVES, int NSPLIT, int BK, bool FUSE5>
__global__ __launch_bounds__(WAVES * 64, 2) void gemm_layer(
    const float* __restrict__ W, const float* __restrict__ bias,
    const short* __restrict__ Xin, short* __restrict__ Out,
    const float* __restrict__ W5, const float* __restrict__ B5,
    float* __restrict__ out5) {
  constexpr int KH    = BK / 16;         // k-quarters per K-step
  constexpr int NT    = K / BK;
  constexpr int NCG   = 8 / NSPLIT;      // 32-wide col groups per block
  constexpr int TILES = NCG * KH;        // 1KB LDS tiles per K-chunk
  constexpr int BM    = WAVES * 32;
  constexpr int MT    = M / BM;
  constexpr int TPW   = TILES / WAVES;   // stage DMA ops per wave per K-step
  constexpr int NS    = 256 / NSPLIT;
  constexpr int EPIW  = 40;              // 80B rows: 8B/16B aligned, modest bank aliasing
  constexpr int PERB  = MT * NSPLIT;     // blocks per sample (grid = 64 * PERB)

  __shared__ __align__(16) short lds[2][TILES * 512];
  __shared__ __align__(16) short epi[WAVES][32][EPIW];

  const int tid = threadIdx.x;
  const int w = tid >> 6, l = tid & 63;
  const int lr = l & 31;   // row (A) / col (B)
  const int lh = l >> 5;   // k-half-group

  // XCD-locality swizzle: keep all PERB sibling blocks of sample b on ONE XCD.
  const int bid = blockIdx.x;
  const int xcd = bid & 7;
  const int i_  = bid >> 3;              // within-XCD slot
  const int b   = xcd + 8 * (i_ / PERB); // sample
  const int rem = i_ % PERB;             // mt * NSPLIT + ns
  const int mt  = rem / NSPLIT;
  const int ns  = rem % NSPLIT;
  const int m0  = mt * BM + w * 32;

  const float* Wb = W + ((size_t)b * M + m0) * K;
  const short* Xb = Xin + (size_t)b * 256 * K + (size_t)ns * NS * K;

  f32x16 acc[NCG] = {};

  auto stage = [&](int buf, int t) {
    const int k0 = t * BK;
#pragma unroll
    for (int i = 0; i < TPW; ++i) {
      const int T  = w * TPW + i;
      const int s  = (T / KH) * 32 + lr;
      const int kk = (T % KH) * 16 + (lh << 3);
      const short* src = Xb + (size_t)s * K + k0 + kk;   // 16B per lane, per-lane addr
      __builtin_amdgcn_global_load_lds(
          (const __attribute__((address_space(1))) void*)src,
          (__attribute__((address_space(3))) void*)&lds[buf][T * 512],
          16, 0, 0);   // wave-uniform LDS base + lane*16 -> fragment-ready layout
    }
  };

  const float* wrow = Wb + (size_t)lr * K + (lh << 3);
  auto load_wfrag = [&](int t) {
    WFrag<BK> f;
#pragma unroll
    for (int h = 0; h < KH; ++h) {
      const float* wp = wrow + t * BK + h * 16;
      f.v[2 * h]     = __builtin_nontemporal_load((const f32x4*)wp);        // W read once: nt
      f.v[2 * h + 1] = __builtin_nontemporal_load((const f32x4*)(wp + 4));  // (no L2/L3 alloc)
    }
    return f;
  };

  WFrag<BK> wn;
  half8 wcH[KH];
  auto cvtW = [&]() {   // wn (fp32, compiler waits exact vmcnt) -> wcH (f16 MFMA A-frags)
#pragma unroll
    for (int h = 0; h < KH; ++h) {
#pragma unroll
      for (int j = 0; j < 4; ++j) {
        wcH[h][j]     = (_Float16)wn.v[2 * h][j];
        wcH[h][j + 4] = (_Float16)wn.v[2 * h + 1][j];
      }
    }
  };

  // ---- prologue: queue = [stage(0), W(0), stage(1)]; cvt W(0) (in-order retire
  //      implies stage(0) done too); issue W(1); barrier -> buf0 visible.
  stage(0, 0);
  asm volatile("" ::: "memory");
  wn = load_wfrag(0);
  asm volatile("" ::: "memory");
  stage(1, 1);
  asm volatile("" ::: "memory");
  cvtW();
  wn = load_wfrag(1);
  asm volatile("" ::: "memory");
  asm volatile("s_barrier" ::: "memory");
  __builtin_amdgcn_sched_barrier(0);

  // ---- main loop: never drain vmcnt to 0; stage(t+2)/W(t+2) span the barrier.
  // At the wait point outstanding = [stage(t+1): TPW, W(t+1): BK/8]; vmcnt(BK/8)
  // retires the stage DMAs, leaves the W loads in flight.
  for (int t = 0; t < NT; ++t) {
    const int cur = t & 1;
#pragma unroll
    for (int h = 0; h < KH; ++h) {
#pragma unroll
      for (int cg = 0; cg < NCG; ++cg) {
        const short8 braw = *(const short8*)&lds[cur][(cg * KH + h) * 512 + l * 8];
        acc[cg] = __builtin_amdgcn_mfma_f32_32x32x16_f16(wcH[h], __builtin_bit_cast(half8, braw),
                                                         acc[cg], 0, 0, 0);
      }
    }
    if (t + 1 < NT) {                      // uniform branch
      if constexpr (BK == 128) {
        asm volatile("s_waitcnt vmcnt(16)" ::: "memory");
      } else {
        asm volatile("s_waitcnt vmcnt(8)" ::: "memory");
      }
      __builtin_amdgcn_sched_barrier(0);
      asm volatile("s_barrier" ::: "memory");   // all waves done reading buf[cur]
      __builtin_amdgcn_sched_barrier(0);
      if (t + 2 < NT) {
        stage(cur, t + 2);                 // refill the buffer just freed by the barrier
        asm volatile("" ::: "memory");
      }
      cvtW();                              // W(t+1): compiler-exact vmcnt wait
      if (t + 2 < NT) {
        wn = load_wfrag(t + 2);
        asm volatile("" ::: "memory");
      }
    }
  }

  // epilogue: bias + sigmoid, per-wave 32x32 LDS transpose
  float brow[16];
#pragma unroll
  for (int r = 0; r < 16; ++r) {
    const int row = (r & 3) + 8 * (r >> 2) + (lh << 2);
    brow[r] = bias[(size_t)b * M + m0 + row];
  }
  const int s_loc = l >> 1, hi = l & 1;
#pragma unroll
  for (int cg = 0; cg < NCG; ++cg) {
    // write phase: lane l owns col s=lr; 4 consecutive m per 8B LDS write
#pragma unroll
    for (int rg = 0; rg < 4; ++rg) {
      short4v pk;
#pragma unroll
      for (int j = 0; j < 4; ++j) {
        const int r = rg * 4 + j;
        float v = acc[cg][r] + brow[r];
        v = 1.0f / (1.0f + __expf(-v));
        pk[j] = (short)f2h_bits(v);
      }
      *(short4v*)&epi[w][lr][rg * 8 + (lh << 2)] = pk;
    }
    if constexpr (!FUSE5) {
      // read phase (same-wave, wave-private buffer), dense 16B global stores
      const short8 r0 = *(const short8*)&epi[w][s_loc][hi * 16];
      const short8 r1 = *(const short8*)&epi[w][s_loc][hi * 16 + 8];
      short* op = Out + ((size_t)b * 256 + ns * NS + cg * 32 + s_loc) * M + m0 + hi * 16;
      *(short8*)op       = r0;
      *(short8*)(op + 8) = r1;
    } else {
      // fc5 tail for this cg's 32 spatial positions (block holds all 128 h4 channels)
      static_assert(!FUSE5 || (M == 128 && WAVES == 4), "FUSE5 needs full-M 4-wave block");
      __syncthreads();                    // epi complete across waves
      const int s_ = tid >> 3, r_ = tid & 7;   // 32 s x 8 cooperating lanes
      const short8 h0 = *(const short8*)&epi[r_ >> 1][s_][(r_ & 1) * 16];
      const short8 h1 = *(const short8*)&epi[r_ >> 1][s_][(r_ & 1) * 16 + 8];
      const float* wp = W5 + b * 128 + r_ * 16;
      const f32x4 w0 = *(const f32x4*)wp;
      const f32x4 w1 = *(const f32x4*)(wp + 4);
      const f32x4 w2 = *(const f32x4*)(wp + 8);
      const f32x4 w3 = *(const f32x4*)(wp + 12);
      float a = 0.f;
#pragma unroll
      for (int j = 0; j < 4; ++j) a += h2f(h0[j]) * w0[j];
#pragma unroll
      for (int j = 0; j < 4; ++j) a += h2f(h0[j + 4]) * w1[j];
#pragma unroll
      for (int j = 0; j < 4; ++j) a += h2f(h1[j]) * w2[j];
#pragma unroll
      for (int j = 0; j < 4; ++j) a += h2f(h1[j + 4]) * w3[j];
      a += __shfl_xor(a, 1);
      a += __shfl_xor(a, 2);
      a += __shfl_xor(a, 4);
      if (r_ == 0) out5[b * 256 + ns * NS + cg * 32 + s_] = 1.0f / (1.0f + __expf(-(a + B5[b])));
      __syncthreads();                    // before next cg overwrites epi
    }
  }
}

extern "C" void kernel_launch(void* const* d_in, const int* in_sizes, int n_in,
                              void* d_out, int out_size, void* d_ws, size_t ws_size,
                              hipStream_t stream) {
  const float* x  = (const float*)d_in[0];
  const float* w1 = (const float*)d_in[1];  const float* b1 = (const float*)d_in[2];
  const float* w2 = (const float*)d_in[3];  const float* b2 = (const float*)d_in[4];
  const float* w3 = (const float*)d_in[5];  const float* b3 = (const float*)d_in[6];
  const float* w4 = (const float*)d_in[7];  const float* b4 = (const float*)d_in[8];
  const float* w5 = (const float*)d_in[9];  const float* b5 = (const float*)d_in[10];

  char* ws = (char*)d_ws;
  short* bufA = (short*)ws;                            // 64 MiB region: xT, then h2
  short* bufB = (short*)(ws + (size_t)67108864);       // 32 MiB region: h1, then h3
  float* out  = (float*)d_out;

  // x -> xT (f16, [B,256,2048])
  transpose_cvt<<<dim3(64, 8, 64), 256, 0, stream>>>(x, bufA);
  // L1: 1024x2048, 8-wave BM=256 (MT=4), grid 256 = 1 block/CU
  gemm_layer<1024, 2048, 8, 1, 64, false><<<256, 512, 0, stream>>>(
      w1, b1, bufA, bufB, nullptr, nullptr, nullptr);                // h1 -> bufB
  // L2: 512x1024 (MT=4, NSPLIT=1): W2 read once, grid 256
  gemm_layer<512, 1024, 4, 1, 64, false><<<256, 256, 0, stream>>>(
      w2, b2, bufB, bufA, nullptr, nullptr, nullptr);                // h2 -> bufA
  // L3: 256x512 (MT=2, NSPLIT=2): W3 x2, grid 256
  gemm_layer<256, 512, 4, 2, 64, false><<<256, 256, 0, stream>>>(
      w3, b3, bufA, bufB, nullptr, nullptr, nullptr);                // h3 -> bufB
  // L4: 128x256 (MT=1, NSPLIT=4): W4 x4, grid 256; fc5 fused
  gemm_layer<128, 256, 4, 4, 64, true><<<256, 256, 0, stream>>>(
      w4, b4, bufB, nullptr, w5, b5, out);
}

// Round 14
// 302.877 us; speedup vs baseline: 1.2990x; 1.2990x over previous
//
#include <hip/hip_runtime.h>
#include <hip/hip_bf16.h>
#include <hip/hip_fp16.h>

// TargetNet: per-sample MLP 2048->1024->512->256->128->1 over 64 samples x 256 spatial.
// R14 = R11 (304.9 us, best) + vectorized transpose_cvt (16B/lane read AND write).
// R13's nt-load experiment regressed +29% (gfx950 nt loses line coalescing) - reverted.
// Old T: 4B/lane global reads, 2B/lane global writes (scalar shorts) - G13 penalty,
// est ~57 us. New T: 64x64 tile, float4 reads, [64][65] LDS (2-way banks = free both
// phases), short8 writes. Est ~33 us.

typedef __attribute__((ext_vector_type(4)))  float    f32x4;
typedef __attribute__((ext_vector_type(16))) float    f32x16;
typedef __attribute__((ext_vector_type(8)))  short    short8;
typedef __attribute__((ext_vector_type(4)))  short    short4v;
typedef __attribute__((ext_vector_type(8)))  _Float16 half8;

__device__ __forceinline__ unsigned short f2h_bits(float f) {
  return __builtin_bit_cast(unsigned short, (_Float16)f);
}
__device__ __forceinline__ float h2f(short h) {
  return (float)__builtin_bit_cast(_Float16, (unsigned short)h);
}

// ---- transpose + convert: x [64][2048][256] f32 -> xT [64][256][2048] f16 ----
// 64c x 64s tile. Read: float4/lane (256B dense per c-row). Write: short8/lane
// (128B dense per s-row). LDS [64][65]: scalar element access both phases, banks
// (r+q+i)%32 and (qc+i+s)%32 both 2-way across a wave = free (m136).
__global__ __launch_bounds__(256) void transpose_cvt(const float* __restrict__ X,
                                                     short* __restrict__ XT) {
  __shared__ float tile[64][65];
  const int b  = blockIdx.z;
  const int c0 = blockIdx.x * 64, s0 = blockIdx.y * 64;
  const int t  = threadIdx.x;
  const float* xp = X + ((size_t)b * 2048 + c0) * 256 + s0;
  const int r0 = t >> 4, q = (t & 15) * 4;
#pragma unroll
  for (int p = 0; p < 4; ++p) {
    const int r = p * 16 + r0;                                  // channel row in tile
    const f32x4 v = *(const f32x4*)&xp[(size_t)r * 256 + q];    // 16B coalesced read
#pragma unroll
    for (int i = 0; i < 4; ++i) tile[r][q + i] = v[i];
  }
  __syncthreads();
  const int s_ = t >> 3, qc = (t & 7) * 8;
  short* op = XT + ((size_t)b * 256 + s0) * 2048 + c0;
#pragma unroll
  for (int p = 0; p < 2; ++p) {
    const int s = p * 32 + s_;
    short8 pk;
#pragma unroll
    for (int i = 0; i < 8; ++i) pk[i] = (short)f2h_bits(tile[qc + i][s]);
    *(short8*)&op[(size_t)s * 2048 + qc] = pk;                  // 16B coalesced write
  }
}

// ---- per-sample GEMM layer with fused bias+sigmoid (optional fused fc5 tail) ----
// C[s, m] = sigmoid( sum_k W[m,k] * X[s,k] + bias[m] ), per sample b.
// A frag: lane l holds row (l&31), k = (l>>5)*8 + j   (f16 cvt from fp32 W, streamed once)
// B frag: lane l holds col (l&31), k = (l>>5)*8 + j   (16B ds_read from frag-ready LDS)
// C frag: col = lane&31, row = (reg&3) + 8*(reg>>2) + 4*(lane>>5)
template <int BK> struct WFrag { f32x4 v[BK / 8]; };

template <int M, int K, int WAVES, int NSPLIT, int BK, bool FUSE5>
__global__ __launch_bounds__(WAVES * 64, 2) void gemm_layer(
    const float* __restrict__ W, const float* __restrict__ bias,
    const short* __restrict__ Xin, short* __restrict__ Out,
    const float* __restrict__ W5, const float* __restrict__ B5,
    float* __restrict__ out5) {
  constexpr int KH    = BK / 16;         // k-quarters per K-step
  constexpr int NT    = K / BK;
  constexpr int NCG   = 8 / NSPLIT;      // 32-wide col groups per block
  constexpr int TILES = NCG * KH;        // 1KB LDS tiles per K-chunk
  constexpr int BM    = WAVES * 32;
  constexpr int MT    = M / BM;
  constexpr int TPW   = TILES / WAVES;   // stage DMA ops per wave per K-step
  constexpr int NS    = 256 / NSPLIT;
  constexpr int EPIW  = 40;              // 80B rows: 8B/16B aligned, modest bank aliasing
  constexpr int PERB  = MT * NSPLIT;     // blocks per sample (grid = 64 * PERB)

  __shared__ __align__(16) short lds[2][TILES * 512];
  __shared__ __align__(16) short epi[WAVES][32][EPIW];

  const int tid = threadIdx.x;
  const int w = tid >> 6, l = tid & 63;
  const int lr = l & 31;   // row (A) / col (B)
  const int lh = l >> 5;   // k-half-group

  // XCD-locality swizzle: keep all PERB sibling blocks of sample b on ONE XCD.
  const int bid = blockIdx.x;
  const int xcd = bid & 7;
  const int i_  = bid >> 3;              // within-XCD slot
  const int b   = xcd + 8 * (i_ / PERB); // sample
  const int rem = i_ % PERB;             // mt * NSPLIT + ns
  const int mt  = rem / NSPLIT;
  const int ns  = rem % NSPLIT;
  const int m0  = mt * BM + w * 32;

  const float* Wb = W + ((size_t)b * M + m0) * K;
  const short* Xb = Xin + (size_t)b * 256 * K + (size_t)ns * NS * K;

  f32x16 acc[NCG] = {};

  auto stage = [&](int buf, int t) {
    const int k0 = t * BK;
#pragma unroll
    for (int i = 0; i < TPW; ++i) {
      const int T  = w * TPW + i;
      const int s  = (T / KH) * 32 + lr;
      const int kk = (T % KH) * 16 + (lh << 3);
      const short* src = Xb + (size_t)s * K + k0 + kk;   // 16B per lane, per-lane addr
      __builtin_amdgcn_global_load_lds(
          (const __attribute__((address_space(1))) void*)src,
          (__attribute__((address_space(3))) void*)&lds[buf][T * 512],
          16, 0, 0);   // wave-uniform LDS base + lane*16 -> fragment-ready layout
    }
  };

  const float* wrow = Wb + (size_t)lr * K + (lh << 3);
  auto load_wfrag = [&](int t) {
    WFrag<BK> f;
#pragma unroll
    for (int h = 0; h < KH; ++h) {
      const float* wp = wrow + t * BK + h * 16;
      f.v[2 * h]     = *(const f32x4*)wp;
      f.v[2 * h + 1] = *(const f32x4*)(wp + 4);
    }
    return f;
  };

  WFrag<BK> wn;
  half8 wcH[KH];
  auto cvtW = [&]() {   // wn (fp32, compiler waits exact vmcnt) -> wcH (f16 MFMA A-frags)
#pragma unroll
    for (int h = 0; h < KH; ++h) {
#pragma unroll
      for (int j = 0; j < 4; ++j) {
        wcH[h][j]     = (_Float16)wn.v[2 * h][j];
        wcH[h][j + 4] = (_Float16)wn.v[2 * h + 1][j];
      }
    }
  };

  // ---- prologue: queue = [stage(0), W(0), stage(1)]; cvt W(0) (in-order retire
  //      implies stage(0) done too); issue W(1); barrier -> buf0 visible.
  stage(0, 0);
  asm volatile("" ::: "memory");
  wn = load_wfrag(0);
  asm volatile("" ::: "memory");
  stage(1, 1);
  asm volatile("" ::: "memory");
  cvtW();
  wn = load_wfrag(1);
  asm volatile("" ::: "memory");
  asm volatile("s_barrier" ::: "memory");
  __builtin_amdgcn_sched_barrier(0);

  // ---- main loop: never drain vmcnt to 0; stage(t+2)/W(t+2) span the barrier.
  for (int t = 0; t < NT; ++t) {
    const int cur = t & 1;
#pragma unroll
    for (int h = 0; h < KH; ++h) {
#pragma unroll
      for (int cg = 0; cg < NCG; ++cg) {
        const short8 braw = *(const short8*)&lds[cur][(cg * KH + h) * 512 + l * 8];
        acc[cg] = __builtin_amdgcn_mfma_f32_32x32x16_f16(wcH[h], __builtin_bit_cast(half8, braw),
                                                         acc[cg], 0, 0, 0);
      }
    }
    if (t + 1 < NT) {                      // uniform branch
      if constexpr (BK == 128) {
        asm volatile("s_waitcnt vmcnt(16)" ::: "memory");
      } else {
        asm volatile("s_waitcnt vmcnt(8)" ::: "memory");
      }
      __builtin_amdgcn_sched_barrier(0);
      asm volatile("s_barrier" ::: "memory");   // all waves done reading buf[cur]
      __builtin_amdgcn_sched_barrier(0);
      if (t + 2 < NT) {
        stage(cur, t + 2);                 // refill the buffer just freed by the barrier
        asm volatile("" ::: "memory");
      }
      cvtW();                              // W(t+1): compiler-exact vmcnt wait
      if (t + 2 < NT) {
        wn = load_wfrag(t + 2);
        asm volatile("" ::: "memory");
      }
    }
  }

  // epilogue: bias + sigmoid, per-wave 32x32 LDS transpose
  float brow[16];
#pragma unroll
  for (int r = 0; r < 16; ++r) {
    const int row = (r & 3) + 8 * (r >> 2) + (lh << 2);
    brow[r] = bias[(size_t)b * M + m0 + row];
  }
  const int s_loc = l >> 1, hi = l & 1;
#pragma unroll
  for (int cg = 0; cg < NCG; ++cg) {
#pragma unroll
    for (int rg = 0; rg < 4; ++rg) {
      short4v pk;
#pragma unroll
      for (int j = 0; j < 4; ++j) {
        const int r = rg * 4 + j;
        float v = acc[cg][r] + brow[r];
        v = 1.0f / (1.0f + __expf(-v));
        pk[j] = (short)f2h_bits(v);
      }
      *(short4v*)&epi[w][lr][rg * 8 + (lh << 2)] = pk;
    }
    if constexpr (!FUSE5) {
      // read phase (same-wave, wave-private buffer), dense 16B global stores
      const short8 r0 = *(const short8*)&epi[w][s_loc][hi * 16];
      const short8 r1 = *(const short8*)&epi[w][s_loc][hi * 16 + 8];
      short* op = Out + ((size_t)b * 256 + ns * NS + cg * 32 + s_loc) * M + m0 + hi * 16;
      *(short8*)op       = r0;
      *(short8*)(op + 8) = r1;
    } else {
      // fc5 tail for this cg's 32 spatial positions (block holds all 128 h4 channels)
      static_assert(!FUSE5 || (M == 128 && WAVES == 4), "FUSE5 needs full-M 4-wave block");
      __syncthreads();                    // epi complete across waves
      const int s_ = tid >> 3, r_ = tid & 7;   // 32 s x 8 cooperating lanes
      const short8 h0 = *(const short8*)&epi[r_ >> 1][s_][(r_ & 1) * 16];
      const short8 h1 = *(const short8*)&epi[r_ >> 1][s_][(r_ & 1) * 16 + 8];
      const float* wp = W5 + b * 128 + r_ * 16;
      const f32x4 w0 = *(const f32x4*)wp;
      const f32x4 w1 = *(const f32x4*)(wp + 4);
      const f32x4 w2 = *(const f32x4*)(wp + 8);
      const f32x4 w3 = *(const f32x4*)(wp + 12);
      float a = 0.f;
#pragma unroll
      for (int j = 0; j < 4; ++j) a += h2f(h0[j]) * w0[j];
#pragma unroll
      for (int j = 0; j < 4; ++j) a += h2f(h0[j + 4]) * w1[j];
#pragma unroll
      for (int j = 0; j < 4; ++j) a += h2f(h1[j]) * w2[j];
#pragma unroll
      for (int j = 0; j < 4; ++j) a += h2f(h1[j + 4]) * w3[j];
      a += __shfl_xor(a, 1);
      a += __shfl_xor(a, 2);
      a += __shfl_xor(a, 4);
      if (r_ == 0) out5[b * 256 + ns * NS + cg * 32 + s_] = 1.0f / (1.0f + __expf(-(a + B5[b])));
      __syncthreads();                    // before next cg overwrites epi
    }
  }
}

extern "C" void kernel_launch(void* const* d_in, const int* in_sizes, int n_in,
                              void* d_out, int out_size, void* d_ws, size_t ws_size,
                              hipStream_t stream) {
  const float* x  = (const float*)d_in[0];
  const float* w1 = (const float*)d_in[1];  const float* b1 = (const float*)d_in[2];
  const float* w2 = (const float*)d_in[3];  const float* b2 = (const float*)d_in[4];
  const float* w3 = (const float*)d_in[5];  const float* b3 = (const float*)d_in[6];
  const float* w4 = (const float*)d_in[7];  const float* b4 = (const float*)d_in[8];
  const float* w5 = (const float*)d_in[9];  const float* b5 = (const float*)d_in[10];

  char* ws = (char*)d_ws;
  short* bufA = (short*)ws;                            // 64 MiB region: xT, then h2
  short* bufB = (short*)(ws + (size_t)67108864);       // 32 MiB region: h1, then h3
  float* out  = (float*)d_out;

  // x -> xT (f16, [B,256,2048]) - vectorized both sides
  transpose_cvt<<<dim3(32, 4, 64), 256, 0, stream>>>(x, bufA);
  // L1: 1024x2048, 8-wave BM=256 (MT=4), grid 256 = 1 block/CU
  gemm_layer<1024, 2048, 8, 1, 64, false><<<256, 512, 0, stream>>>(
      w1, b1, bufA, bufB, nullptr, nullptr, nullptr);                // h1 -> bufB
  // L2: 512x1024 (MT=4, NSPLIT=1): W2 read once, grid 256
  gemm_layer<512, 1024, 4, 1, 64, false><<<256, 256, 0, stream>>>(
      w2, b2, bufB, bufA, nullptr, nullptr, nullptr);                // h2 -> bufA
  // L3: 256x512 (MT=2, NSPLIT=2): W3 x2, grid 256
  gemm_layer<256, 512, 4, 2, 64, false><<<256, 256, 0, stream>>>(
      w3, b3, bufA, bufB, nullptr, nullptr, nullptr);                // h3 -> bufB
  // L4: 128x256 (MT=1, NSPLIT=4): W4 x4, grid 256; fc5 fused
  gemm_layer<128, 256, 4, 4, 64, true><<<256, 256, 0, stream>>>(
      w4, b4, bufB, nullptr, w5, b5, out);
}